// Round 11
// baseline (575.592 us; speedup 1.0000x reference)
//
#include <hip/hip_runtime.h>
#include <math.h>

// SSMInterBlock fused v8: occupancy doubling on the barrier-free v7 structure.
// v7 (284us, best): VALUBusy 46%, occupancy 39% (~3 waves/SIMD), 0 bank
// conflicts, no pipe saturated -> latency-bound at low occupancy. v8: (1) YZ
// region merged into SU (u's LDS copy dead after P-B; intra-wave DS ordering
// makes in-place overwrite safe) -> LDS 27.1->14.7 KB/block; (2)
// __launch_bounds__(256,8) so 8 blocks/CU (32 waves) become reachable at
// VGPR=64. Everything else identical to v7.

#define THREADS 256
#define SEQ_PB  4
#define DM      96
#define DE      192
#define NJ      384
#define NST     16
#define RNK     6
#define NC      38

#define WP      920            // per-wave LDS region pitch (floats)
#define SU_OFF  0              // u d-major quads [d*4+l], 768 f; yz reuses this
#define XD_OFF  768            // x_dbl quads [c*4+l], 152 f
#define YZ_OFF  0              // yz overwrites u region (dead after P-B)

// ws float offsets
#define OFF_W1T 0              // [96][384]  w1t[dd][j] = w_in[j][dd]
#define OFF_WO  36864          // [192][96]  wo[d][dd]  = w_out[dd][d]
#define OFF_NAT 55296          // [16][192]  nat[n][d]  = -exp(a_logs[d][n])
#define OFF_DTT 58368          // [6][192]   dtt[r][d]  = w_dt[d][r]
                               // end 59520 floats = 238,080 B

__device__ __forceinline__ float softplus_f(float x) {
    return fmaxf(x, 0.f) + log1pf(__expf(-fabsf(x)));
}
__device__ __forceinline__ float silu_f(float x) {
    return x / (1.f + __expf(-x));
}
__device__ __forceinline__ float4 silu4(float4 v) {
    v.x = silu_f(v.x); v.y = silu_f(v.y); v.z = silu_f(v.z); v.w = silu_f(v.w);
    return v;
}
__device__ __forceinline__ float4 fma4(float w, float4 x, float4 a) {
    a.x = fmaf(w, x.x, a.x); a.y = fmaf(w, x.y, a.y);
    a.z = fmaf(w, x.z, a.z); a.w = fmaf(w, x.w, a.w);
    return a;
}

__global__ void prep_weights(const float* __restrict__ w_in,
                             const float* __restrict__ w_out,
                             const float* __restrict__ a_logs,
                             const float* __restrict__ w_dt,
                             float* __restrict__ ws) {
    int t0 = blockIdx.x * blockDim.x + threadIdx.x;
    int stride = gridDim.x * blockDim.x;
    for (int t = t0; t < DM * NJ; t += stride) {          // W1^T
        int dd = t / NJ, j = t % NJ;
        ws[OFF_W1T + t] = w_in[j * DM + dd];
    }
    for (int t = t0; t < DE * DM; t += stride) {          // Wout^T
        int d = t / DM, dd = t % DM;
        ws[OFF_WO + t] = w_out[dd * DE + d];
    }
    for (int t = t0; t < NST * DE; t += stride) {         // -exp(A_logs)^T
        int n = t / DE, d = t % DE;
        ws[OFF_NAT + t] = -__expf(a_logs[d * NST + n]);
    }
    for (int t = t0; t < RNK * DE; t += stride) {         // w_dt^T
        int r = t / DE, d = t % DE;
        ws[OFF_DTT + t] = w_dt[d * RNK + r];
    }
}

__global__ __launch_bounds__(THREADS, 8)
void ssm_fused8(const float* __restrict__ x,       // [nseq][384] = [seq][d][l]
                const float* __restrict__ w_xp,    // [38][192] row c contiguous
                const float* __restrict__ b_dt,    // [192]
                const float* __restrict__ dvec,    // [192]
                const float* __restrict__ gamma_,  // [192]
                const float* __restrict__ beta_,   // [192]
                const float* __restrict__ ws,
                float* __restrict__ out)           // [nseq][384] = [seq][dd][l]
{
    __shared__ float lds[SEQ_PB * WP];   // 14,720 B; 4 private per-wave regions

    const int tid  = threadIdx.x;
    const int lane = tid & 63;
    const int blk  = blockIdx.x;
    const int wv   = __builtin_amdgcn_readfirstlane(tid >> 6);  // wave = seq
    float* W = lds + wv * WP;

    // ---------- P-A: xz = silu(x @ W1^T). lane owns j = lane + 64m, m=0..5.
    // Weights b32 lane-coalesced; x wave-uniform -> s_loads.
    float4 u0, u1, u2, z0, z1, z2;
    {
        const float4* xs4 = (const float4*)(x + ((size_t)blk * SEQ_PB + wv) * NJ);
        const float* wb = ws + OFF_W1T + lane;
        float4 zz = make_float4(0.f, 0.f, 0.f, 0.f);
        float4 a0 = zz, a1 = zz, a2 = zz, a3 = zz, a4 = zz, a5 = zz;
        #pragma unroll 1
        for (int dds = 0; dds < DM; dds += 8) {
            float4 xv0 = xs4[dds + 0], xv1 = xs4[dds + 1];
            float4 xv2 = xs4[dds + 2], xv3 = xs4[dds + 3];
            float4 xv4 = xs4[dds + 4], xv5 = xs4[dds + 5];
            float4 xv6 = xs4[dds + 6], xv7 = xs4[dds + 7];
#define PA_I(XV, I) { \
            const float* wr_ = wb + (dds + (I)) * NJ; \
            float w_; \
            w_ = wr_[0];   a0 = fma4(w_, XV, a0); \
            w_ = wr_[64];  a1 = fma4(w_, XV, a1); \
            w_ = wr_[128]; a2 = fma4(w_, XV, a2); \
            w_ = wr_[192]; a3 = fma4(w_, XV, a3); \
            w_ = wr_[256]; a4 = fma4(w_, XV, a4); \
            w_ = wr_[320]; a5 = fma4(w_, XV, a5); }
            PA_I(xv0, 0) PA_I(xv1, 1) PA_I(xv2, 2) PA_I(xv3, 3)
            PA_I(xv4, 4) PA_I(xv5, 5) PA_I(xv6, 6) PA_I(xv7, 7)
#undef PA_I
        }
        u0 = silu4(a0); u1 = silu4(a1); u2 = silu4(a2);   // d = lane+64k
        z0 = silu4(a3); z1 = silu4(a4); z2 = silu4(a5);   // z for same d
        // u to per-wave LDS (d-major quads) for P-B's cross-d reduction
        *(float4*)&W[SU_OFF + 4 * lane]         = u0;
        *(float4*)&W[SU_OFF + 4 * (lane + 64)]  = u1;
        *(float4*)&W[SU_OFF + 4 * (lane + 128)] = u2;
    }
    // (no barrier: intra-wave DS ops are in-order)

    // ---------- P-B: x_dbl[c][l] = sum_d u[d][l] * w_xp[c][d]; c = lane < 38
    if (lane < NC) {
        const float* wc = w_xp + lane * DE;
        float4 cacc = make_float4(0.f, 0.f, 0.f, 0.f);
        #pragma unroll 4
        for (int dq = 0; dq < DE / 4; ++dq) {
            float4 wq = *(const float4*)&wc[4 * dq];
            float4 q0 = *(const float4*)&W[SU_OFF + 4 * (4 * dq + 0)];
            float4 q1 = *(const float4*)&W[SU_OFF + 4 * (4 * dq + 1)];
            float4 q2 = *(const float4*)&W[SU_OFF + 4 * (4 * dq + 2)];
            float4 q3 = *(const float4*)&W[SU_OFF + 4 * (4 * dq + 3)];
            cacc = fma4(wq.x, q0, cacc); cacc = fma4(wq.y, q1, cacc);
            cacc = fma4(wq.z, q2, cacc); cacc = fma4(wq.w, q3, cacc);
        }
        *(float4*)&W[XD_OFF + 4 * lane] = cacc;
    }

    // ---------- P-C: delta + selective scan; lane owns d = lane + 64k
    float4 y_0, y_1, y_2;
#define SCAN_K(K, U4, YOUT) { \
    const int d = lane + 64 * (K); \
    float4 t0 = *(const float4*)&W[XD_OFF + 0]; \
    float4 t1 = *(const float4*)&W[XD_OFF + 4]; \
    float4 t2 = *(const float4*)&W[XD_OFF + 8]; \
    float4 t3 = *(const float4*)&W[XD_OFF + 12]; \
    float4 t4 = *(const float4*)&W[XD_OFF + 16]; \
    float4 t5 = *(const float4*)&W[XD_OFF + 20]; \
    const float* dtt = ws + OFF_DTT + d; \
    float r0 = dtt[0], r1 = dtt[192], r2 = dtt[384]; \
    float r3 = dtt[576], r4 = dtt[768], r5 = dtt[960]; \
    float d0 = r0 * t0.x, d1 = r0 * t0.y, d2 = r0 * t0.z, d3 = r0 * t0.w; \
    d0 = fmaf(r1, t1.x, d0); d1 = fmaf(r1, t1.y, d1); \
    d2 = fmaf(r1, t1.z, d2); d3 = fmaf(r1, t1.w, d3); \
    d0 = fmaf(r2, t2.x, d0); d1 = fmaf(r2, t2.y, d1); \
    d2 = fmaf(r2, t2.z, d2); d3 = fmaf(r2, t2.w, d3); \
    d0 = fmaf(r3, t3.x, d0); d1 = fmaf(r3, t3.y, d1); \
    d2 = fmaf(r3, t3.z, d2); d3 = fmaf(r3, t3.w, d3); \
    d0 = fmaf(r4, t4.x, d0); d1 = fmaf(r4, t4.y, d1); \
    d2 = fmaf(r4, t4.z, d2); d3 = fmaf(r4, t4.w, d3); \
    d0 = fmaf(r5, t5.x, d0); d1 = fmaf(r5, t5.y, d1); \
    d2 = fmaf(r5, t5.z, d2); d3 = fmaf(r5, t5.w, d3); \
    float bias = b_dt[d]; \
    float dl0 = softplus_f(d0 + bias), dl1 = softplus_f(d1 + bias); \
    float dl2 = softplus_f(d2 + bias), dl3 = softplus_f(d3 + bias); \
    float du0 = dl0 * U4.x, du1 = dl1 * U4.y; \
    float du2 = dl2 * U4.z, du3 = dl3 * U4.w; \
    const float* natp = ws + OFF_NAT + d; \
    float y0 = 0.f, y1 = 0.f, y2 = 0.f, y3 = 0.f; \
    _Pragma("unroll") \
    for (int n = 0; n < NST; ++n) { \
        float an = natp[n * DE]; \
        float4 bn = *(const float4*)&W[XD_OFF + (RNK + n) * 4]; \
        float4 cn = *(const float4*)&W[XD_OFF + (RNK + NST + n) * 4]; \
        float h = du0 * bn.x; \
        y0 = fmaf(h, cn.x, y0); \
        h = fmaf(du1, bn.y, __expf(dl1 * an) * h); \
        y1 = fmaf(h, cn.y, y1); \
        h = fmaf(du2, bn.z, __expf(dl2 * an) * h); \
        y2 = fmaf(h, cn.z, y2); \
        h = fmaf(du3, bn.w, __expf(dl3 * an) * h); \
        y3 = fmaf(h, cn.w, y3); \
    } \
    float Dd = dvec[d]; \
    YOUT.x = fmaf(Dd, U4.x, y0); YOUT.y = fmaf(Dd, U4.y, y1); \
    YOUT.z = fmaf(Dd, U4.z, y2); YOUT.w = fmaf(Dd, U4.w, y3); }
    SCAN_K(0, u0, y_0)
    SCAN_K(1, u1, y_1)
    SCAN_K(2, u2, y_2)
#undef SCAN_K

    // ---------- P-LN: mean/rstd over 192 d per l, via 64-lane butterfly
    float4 mu4, rs4;
    {
        float4 s4, q4;
        s4.x = y_0.x + y_1.x + y_2.x; s4.y = y_0.y + y_1.y + y_2.y;
        s4.z = y_0.z + y_1.z + y_2.z; s4.w = y_0.w + y_1.w + y_2.w;
        q4.x = y_0.x * y_0.x + y_1.x * y_1.x + y_2.x * y_2.x;
        q4.y = y_0.y * y_0.y + y_1.y * y_1.y + y_2.y * y_2.y;
        q4.z = y_0.z * y_0.z + y_1.z * y_1.z + y_2.z * y_2.z;
        q4.w = y_0.w * y_0.w + y_1.w * y_1.w + y_2.w * y_2.w;
        #pragma unroll
        for (int off = 1; off < 64; off <<= 1) {
            s4.x += __shfl_xor(s4.x, off); s4.y += __shfl_xor(s4.y, off);
            s4.z += __shfl_xor(s4.z, off); s4.w += __shfl_xor(s4.w, off);
            q4.x += __shfl_xor(q4.x, off); q4.y += __shfl_xor(q4.y, off);
            q4.z += __shfl_xor(q4.z, off); q4.w += __shfl_xor(q4.w, off);
        }
        const float inv = 1.f / DE;
        mu4.x = s4.x * inv; mu4.y = s4.y * inv;
        mu4.z = s4.z * inv; mu4.w = s4.w * inv;
        rs4.x = rsqrtf(q4.x * inv - mu4.x * mu4.x + 1e-5f);
        rs4.y = rsqrtf(q4.y * inv - mu4.y * mu4.y + 1e-5f);
        rs4.z = rsqrtf(q4.z * inv - mu4.z * mu4.z + 1e-5f);
        rs4.w = rsqrtf(q4.w * inv - mu4.w * mu4.w + 1e-5f);
    }

    // ---------- P-LN2: yz = ((y-mu)*rstd*gamma + beta) * z -> overwrites u region
    // (safe: P-B's reads of SU precede these writes in wave program order)
#define LN2_K(K, Y4, Z4) { \
    const int d = lane + 64 * (K); \
    float ga = gamma_[d], be = beta_[d]; \
    float4 o; \
    o.x = fmaf((Y4.x - mu4.x) * rs4.x, ga, be) * Z4.x; \
    o.y = fmaf((Y4.y - mu4.y) * rs4.y, ga, be) * Z4.y; \
    o.z = fmaf((Y4.z - mu4.z) * rs4.z, ga, be) * Z4.z; \
    o.w = fmaf((Y4.w - mu4.w) * rs4.w, ga, be) * Z4.w; \
    *(float4*)&W[YZ_OFF + 4 * d] = o; }
    LN2_K(0, y_0, z0)
    LN2_K(1, y_1, z1)
    LN2_K(2, y_2, z2)
#undef LN2_K

    // ---------- P-D: out[dd][l] = sum_d yz[d][l] * wo[d][dd]
    {
        const int dd1 = lane;
        const int dd2 = 64 + (lane & 31);
        const float* wo1 = ws + OFF_WO + dd1;
        const float* wo2 = ws + OFF_WO + dd2;
        float4 o1 = make_float4(0.f, 0.f, 0.f, 0.f);
        float4 o2 = make_float4(0.f, 0.f, 0.f, 0.f);
        #pragma unroll 4
        for (int d = 0; d < DE; ++d) {
            float4 yz = *(const float4*)&W[YZ_OFF + 4 * d];   // b128 broadcast
            float w1 = wo1[d * DM];                           // b32 coalesced
            float w2 = wo2[d * DM];
            o1 = fma4(w1, yz, o1);
            o2 = fma4(w2, yz, o2);
        }
        float* ob = out + (size_t)blk * (SEQ_PB * NJ) + wv * NJ;
        *(float4*)&ob[4 * dd1] = o1;
        if (lane < 32)
            *(float4*)&ob[4 * dd2] = o2;
    }
}

extern "C" void kernel_launch(void* const* d_in, const int* in_sizes, int n_in,
                              void* d_out, int out_size, void* d_ws, size_t ws_size,
                              hipStream_t stream) {
    (void)n_in; (void)ws_size; (void)out_size;
    int nseq = in_sizes[0] / NJ;            // 12544 = 4*56*56
    int grid = nseq / SEQ_PB;               // 3136 blocks
    if (grid < 1) grid = 1;
    float* ws = (float*)d_ws;               // 238 KB used

    prep_weights<<<64, THREADS, 0, stream>>>(
        (const float*)d_in[1],  // in_proj_w
        (const float*)d_in[9],  // out_proj_w
        (const float*)d_in[5],  // A_logs
        (const float*)d_in[3],  // dt_projs_weight
        ws);

    ssm_fused8<<<grid, THREADS, 0, stream>>>(
        (const float*)d_in[0],  // x
        (const float*)d_in[2],  // x_proj_weight
        (const float*)d_in[4],  // dt_projs_bias
        (const float*)d_in[6],  // Ds
        (const float*)d_in[7],  // ln_gamma
        (const float*)d_in[8],  // ln_beta
        ws,
        (float*)d_out);
}

// Round 12
// 278.243 us; speedup vs baseline: 2.0687x; 2.0687x over previous
//
#include <hip/hip_runtime.h>
#include <math.h>

// SSMInterBlock fused v9: 2 sequences per wave (arithmetic-intensity doubling).
// Ladder: v7 284us (barrier-free, VALUBusy 46%, occ 39%, VMEM-latency bound).
// v8 (256,8) FAILED: allocator squeezed VGPR 64->32, scratch spill exploded
// (FETCH 175->390 MB, WRITE 323->740 MB), 504us. Occupancy is the wrong lever.
// v9: each wave processes 2 seqs -> every P-A/P-B/P-D weight load feeds two
// independent FMA chains (per-seq VMEM halves, 2x ILP covers L2 latency).
// __launch_bounds__(256,2): the config proven in v1 to give VGPR=128 (no
// spill) for the ~90-reg live set. Barrier-free per-wave-private LDS kept.

#define THREADS 256
#define SEQ_PB  8              // seqs per block (2 per wave)
#define DM      96
#define DE      192
#define NJ      384
#define NST     16
#define RNK     6
#define NC      38

#define SWP     920            // per-SEQ LDS region (floats)
#define SU_OFF  0              // u d-major quads [d*4+l], 768 f; yz reuses this
#define XD_OFF  768            // x_dbl quads [c*4+l], 152 f

// ws float offsets
#define OFF_W1T 0              // [96][384]  w1t[dd][j] = w_in[j][dd]
#define OFF_WO  36864          // [192][96]  wo[d][dd]  = w_out[dd][d]
#define OFF_NAT 55296          // [16][192]  nat[n][d]  = -exp(a_logs[d][n])
#define OFF_DTT 58368          // [6][192]   dtt[r][d]  = w_dt[d][r]

__device__ __forceinline__ float softplus_f(float x) {
    return fmaxf(x, 0.f) + log1pf(__expf(-fabsf(x)));
}
__device__ __forceinline__ float silu_f(float x) {
    return x / (1.f + __expf(-x));
}
__device__ __forceinline__ float4 silu4(float4 v) {
    v.x = silu_f(v.x); v.y = silu_f(v.y); v.z = silu_f(v.z); v.w = silu_f(v.w);
    return v;
}
__device__ __forceinline__ float4 fma4(float w, float4 x, float4 a) {
    a.x = fmaf(w, x.x, a.x); a.y = fmaf(w, x.y, a.y);
    a.z = fmaf(w, x.z, a.z); a.w = fmaf(w, x.w, a.w);
    return a;
}

__global__ void prep_weights(const float* __restrict__ w_in,
                             const float* __restrict__ w_out,
                             const float* __restrict__ a_logs,
                             const float* __restrict__ w_dt,
                             float* __restrict__ ws) {
    int t0 = blockIdx.x * blockDim.x + threadIdx.x;
    int stride = gridDim.x * blockDim.x;
    for (int t = t0; t < DM * NJ; t += stride) {          // W1^T
        int dd = t / NJ, j = t % NJ;
        ws[OFF_W1T + t] = w_in[j * DM + dd];
    }
    for (int t = t0; t < DE * DM; t += stride) {          // Wout^T
        int d = t / DM, dd = t % DM;
        ws[OFF_WO + t] = w_out[dd * DE + d];
    }
    for (int t = t0; t < NST * DE; t += stride) {         // -exp(A_logs)^T
        int n = t / DE, d = t % DE;
        ws[OFF_NAT + t] = -__expf(a_logs[d * NST + n]);
    }
    for (int t = t0; t < RNK * DE; t += stride) {         // w_dt^T
        int r = t / DE, d = t % DE;
        ws[OFF_DTT + t] = w_dt[d * RNK + r];
    }
}

__global__ __launch_bounds__(THREADS, 2)
void ssm_fused9(const float* __restrict__ x,       // [nseq][384] = [seq][d][l]
                const float* __restrict__ w_xp,    // [38][192] row c contiguous
                const float* __restrict__ b_dt,    // [192]
                const float* __restrict__ dvec,    // [192]
                const float* __restrict__ gamma_,  // [192]
                const float* __restrict__ beta_,   // [192]
                const float* __restrict__ ws,
                float* __restrict__ out)           // [nseq][384] = [seq][dd][l]
{
    __shared__ float lds[4 * 2 * SWP];   // 29,440 B; per-wave: 2 seq regions

    const int lane = threadIdx.x & 63;
    const int blk  = blockIdx.x;
    const int wv   = __builtin_amdgcn_readfirstlane((int)(threadIdx.x >> 6));
    float* WA = lds + wv * (2 * SWP);
    float* WB = WA + SWP;

    // ---------- P-A: xz = silu(x @ W1^T) for seqs A and B sharing weight loads.
    // lane owns j = lane + 64m, m=0..5. Weights b32 lane-coalesced; x -> s_loads.
    float4 uA0, uA1, uA2, zA0, zA1, zA2;
    float4 uB0, uB1, uB2, zB0, zB1, zB2;
    {
        const float4* xa4 = (const float4*)(x + ((size_t)blk * SEQ_PB + 2 * wv) * NJ);
        const float4* xb4 = xa4 + NJ / 4;
        const float* wb = ws + OFF_W1T + lane;
        float4 zz = make_float4(0.f, 0.f, 0.f, 0.f);
        float4 aA0 = zz, aA1 = zz, aA2 = zz, aA3 = zz, aA4 = zz, aA5 = zz;
        float4 aB0 = zz, aB1 = zz, aB2 = zz, aB3 = zz, aB4 = zz, aB5 = zz;
        #pragma unroll 1
        for (int dds = 0; dds < DM; dds += 4) {
            float4 xvA0 = xa4[dds + 0], xvA1 = xa4[dds + 1];
            float4 xvA2 = xa4[dds + 2], xvA3 = xa4[dds + 3];
            float4 xvB0 = xb4[dds + 0], xvB1 = xb4[dds + 1];
            float4 xvB2 = xb4[dds + 2], xvB3 = xb4[dds + 3];
#define PA_I(XVA, XVB, I) { \
            const float* wr_ = wb + (dds + (I)) * NJ; \
            float w_; \
            w_ = wr_[0];   aA0 = fma4(w_, XVA, aA0); aB0 = fma4(w_, XVB, aB0); \
            w_ = wr_[64];  aA1 = fma4(w_, XVA, aA1); aB1 = fma4(w_, XVB, aB1); \
            w_ = wr_[128]; aA2 = fma4(w_, XVA, aA2); aB2 = fma4(w_, XVB, aB2); \
            w_ = wr_[192]; aA3 = fma4(w_, XVA, aA3); aB3 = fma4(w_, XVB, aB3); \
            w_ = wr_[256]; aA4 = fma4(w_, XVA, aA4); aB4 = fma4(w_, XVB, aB4); \
            w_ = wr_[320]; aA5 = fma4(w_, XVA, aA5); aB5 = fma4(w_, XVB, aB5); }
            PA_I(xvA0, xvB0, 0) PA_I(xvA1, xvB1, 1)
            PA_I(xvA2, xvB2, 2) PA_I(xvA3, xvB3, 3)
#undef PA_I
        }
        uA0 = silu4(aA0); uA1 = silu4(aA1); uA2 = silu4(aA2);
        zA0 = silu4(aA3); zA1 = silu4(aA4); zA2 = silu4(aA5);
        uB0 = silu4(aB0); uB1 = silu4(aB1); uB2 = silu4(aB2);
        zB0 = silu4(aB3); zB1 = silu4(aB4); zB2 = silu4(aB5);
        *(float4*)&WA[SU_OFF + 4 * lane]         = uA0;
        *(float4*)&WA[SU_OFF + 4 * (lane + 64)]  = uA1;
        *(float4*)&WA[SU_OFF + 4 * (lane + 128)] = uA2;
        *(float4*)&WB[SU_OFF + 4 * lane]         = uB0;
        *(float4*)&WB[SU_OFF + 4 * (lane + 64)]  = uB1;
        *(float4*)&WB[SU_OFF + 4 * (lane + 128)] = uB2;
    }
    // (no barrier: intra-wave DS ops are in-order)

    // ---------- P-B: x_dbl[c][l] for both seqs, sharing w_xp loads; c = lane < 38
    if (lane < NC) {
        const float* wc = w_xp + lane * DE;
        float4 cA = make_float4(0.f, 0.f, 0.f, 0.f);
        float4 cB = make_float4(0.f, 0.f, 0.f, 0.f);
        #pragma unroll 4
        for (int dq = 0; dq < DE / 4; ++dq) {
            float4 wq = *(const float4*)&wc[4 * dq];
            float4 qA0 = *(const float4*)&WA[SU_OFF + 4 * (4 * dq + 0)];
            float4 qA1 = *(const float4*)&WA[SU_OFF + 4 * (4 * dq + 1)];
            float4 qA2 = *(const float4*)&WA[SU_OFF + 4 * (4 * dq + 2)];
            float4 qA3 = *(const float4*)&WA[SU_OFF + 4 * (4 * dq + 3)];
            float4 qB0 = *(const float4*)&WB[SU_OFF + 4 * (4 * dq + 0)];
            float4 qB1 = *(const float4*)&WB[SU_OFF + 4 * (4 * dq + 1)];
            float4 qB2 = *(const float4*)&WB[SU_OFF + 4 * (4 * dq + 2)];
            float4 qB3 = *(const float4*)&WB[SU_OFF + 4 * (4 * dq + 3)];
            cA = fma4(wq.x, qA0, cA); cA = fma4(wq.y, qA1, cA);
            cA = fma4(wq.z, qA2, cA); cA = fma4(wq.w, qA3, cA);
            cB = fma4(wq.x, qB0, cB); cB = fma4(wq.y, qB1, cB);
            cB = fma4(wq.z, qB2, cB); cB = fma4(wq.w, qB3, cB);
        }
        *(float4*)&WA[XD_OFF + 4 * lane] = cA;
        *(float4*)&WB[XD_OFF + 4 * lane] = cB;
    }

    // ---------- P-C/LN/LN2 per seq (A then B); yz overwrites u region
#define SCAN_K(WREG, K, U4, YOUT) { \
    const int d = lane + 64 * (K); \
    float4 t0 = *(const float4*)&WREG[XD_OFF + 0]; \
    float4 t1 = *(const float4*)&WREG[XD_OFF + 4]; \
    float4 t2 = *(const float4*)&WREG[XD_OFF + 8]; \
    float4 t3 = *(const float4*)&WREG[XD_OFF + 12]; \
    float4 t4 = *(const float4*)&WREG[XD_OFF + 16]; \
    float4 t5 = *(const float4*)&WREG[XD_OFF + 20]; \
    const float* dtt = ws + OFF_DTT + d; \
    float r0 = dtt[0], r1 = dtt[192], r2 = dtt[384]; \
    float r3 = dtt[576], r4 = dtt[768], r5 = dtt[960]; \
    float d0 = r0 * t0.x, d1 = r0 * t0.y, d2 = r0 * t0.z, d3 = r0 * t0.w; \
    d0 = fmaf(r1, t1.x, d0); d1 = fmaf(r1, t1.y, d1); \
    d2 = fmaf(r1, t1.z, d2); d3 = fmaf(r1, t1.w, d3); \
    d0 = fmaf(r2, t2.x, d0); d1 = fmaf(r2, t2.y, d1); \
    d2 = fmaf(r2, t2.z, d2); d3 = fmaf(r2, t2.w, d3); \
    d0 = fmaf(r3, t3.x, d0); d1 = fmaf(r3, t3.y, d1); \
    d2 = fmaf(r3, t3.z, d2); d3 = fmaf(r3, t3.w, d3); \
    d0 = fmaf(r4, t4.x, d0); d1 = fmaf(r4, t4.y, d1); \
    d2 = fmaf(r4, t4.z, d2); d3 = fmaf(r4, t4.w, d3); \
    d0 = fmaf(r5, t5.x, d0); d1 = fmaf(r5, t5.y, d1); \
    d2 = fmaf(r5, t5.z, d2); d3 = fmaf(r5, t5.w, d3); \
    float bias = b_dt[d]; \
    float dl0 = softplus_f(d0 + bias), dl1 = softplus_f(d1 + bias); \
    float dl2 = softplus_f(d2 + bias), dl3 = softplus_f(d3 + bias); \
    float du0 = dl0 * U4.x, du1 = dl1 * U4.y; \
    float du2 = dl2 * U4.z, du3 = dl3 * U4.w; \
    const float* natp = ws + OFF_NAT + d; \
    float y0 = 0.f, y1 = 0.f, y2 = 0.f, y3 = 0.f; \
    _Pragma("unroll") \
    for (int n = 0; n < NST; ++n) { \
        float an = natp[n * DE]; \
        float4 bn = *(const float4*)&WREG[XD_OFF + (RNK + n) * 4]; \
        float4 cn = *(const float4*)&WREG[XD_OFF + (RNK + NST + n) * 4]; \
        float h = du0 * bn.x; \
        y0 = fmaf(h, cn.x, y0); \
        h = fmaf(du1, bn.y, __expf(dl1 * an) * h); \
        y1 = fmaf(h, cn.y, y1); \
        h = fmaf(du2, bn.z, __expf(dl2 * an) * h); \
        y2 = fmaf(h, cn.z, y2); \
        h = fmaf(du3, bn.w, __expf(dl3 * an) * h); \
        y3 = fmaf(h, cn.w, y3); \
    } \
    float Dd = dvec[d]; \
    YOUT.x = fmaf(Dd, U4.x, y0); YOUT.y = fmaf(Dd, U4.y, y1); \
    YOUT.z = fmaf(Dd, U4.z, y2); YOUT.w = fmaf(Dd, U4.w, y3); }

#define LN_STATS(Y0, Y1, Y2, MU, RS) { \
    float4 s4, q4; \
    s4.x = Y0.x + Y1.x + Y2.x; s4.y = Y0.y + Y1.y + Y2.y; \
    s4.z = Y0.z + Y1.z + Y2.z; s4.w = Y0.w + Y1.w + Y2.w; \
    q4.x = Y0.x * Y0.x + Y1.x * Y1.x + Y2.x * Y2.x; \
    q4.y = Y0.y * Y0.y + Y1.y * Y1.y + Y2.y * Y2.y; \
    q4.z = Y0.z * Y0.z + Y1.z * Y1.z + Y2.z * Y2.z; \
    q4.w = Y0.w * Y0.w + Y1.w * Y1.w + Y2.w * Y2.w; \
    _Pragma("unroll") \
    for (int off = 1; off < 64; off <<= 1) { \
        s4.x += __shfl_xor(s4.x, off); s4.y += __shfl_xor(s4.y, off); \
        s4.z += __shfl_xor(s4.z, off); s4.w += __shfl_xor(s4.w, off); \
        q4.x += __shfl_xor(q4.x, off); q4.y += __shfl_xor(q4.y, off); \
        q4.z += __shfl_xor(q4.z, off); q4.w += __shfl_xor(q4.w, off); \
    } \
    const float inv = 1.f / DE; \
    MU.x = s4.x * inv; MU.y = s4.y * inv; \
    MU.z = s4.z * inv; MU.w = s4.w * inv; \
    RS.x = rsqrtf(q4.x * inv - MU.x * MU.x + 1e-5f); \
    RS.y = rsqrtf(q4.y * inv - MU.y * MU.y + 1e-5f); \
    RS.z = rsqrtf(q4.z * inv - MU.z * MU.z + 1e-5f); \
    RS.w = rsqrtf(q4.w * inv - MU.w * MU.w + 1e-5f); }

#define LN2_K(WREG, K, Y4, Z4, MU, RS) { \
    const int d = lane + 64 * (K); \
    float ga = gamma_[d], be = beta_[d]; \
    float4 o; \
    o.x = fmaf((Y4.x - MU.x) * RS.x, ga, be) * Z4.x; \
    o.y = fmaf((Y4.y - MU.y) * RS.y, ga, be) * Z4.y; \
    o.z = fmaf((Y4.z - MU.z) * RS.z, ga, be) * Z4.z; \
    o.w = fmaf((Y4.w - MU.w) * RS.w, ga, be) * Z4.w; \
    *(float4*)&WREG[SU_OFF + 4 * d] = o; }

    {   // seq A
        float4 yA0, yA1, yA2, muA, rsA;
        SCAN_K(WA, 0, uA0, yA0)
        SCAN_K(WA, 1, uA1, yA1)
        SCAN_K(WA, 2, uA2, yA2)
        LN_STATS(yA0, yA1, yA2, muA, rsA)
        LN2_K(WA, 0, yA0, zA0, muA, rsA)
        LN2_K(WA, 1, yA1, zA1, muA, rsA)
        LN2_K(WA, 2, yA2, zA2, muA, rsA)
    }
    {   // seq B
        float4 yB0, yB1, yB2, muB, rsB;
        SCAN_K(WB, 0, uB0, yB0)
        SCAN_K(WB, 1, uB1, yB1)
        SCAN_K(WB, 2, uB2, yB2)
        LN_STATS(yB0, yB1, yB2, muB, rsB)
        LN2_K(WB, 0, yB0, zB0, muB, rsB)
        LN2_K(WB, 1, yB1, zB1, muB, rsB)
        LN2_K(WB, 2, yB2, zB2, muB, rsB)
    }
#undef SCAN_K
#undef LN_STATS
#undef LN2_K

    // ---------- P-D: out for both seqs, sharing Wout loads
    {
        const int dd1 = lane;
        const int dd2 = 64 + (lane & 31);
        const float* wo1 = ws + OFF_WO + dd1;
        const float* wo2 = ws + OFF_WO + dd2;
        float4 o1A = make_float4(0.f, 0.f, 0.f, 0.f);
        float4 o2A = make_float4(0.f, 0.f, 0.f, 0.f);
        float4 o1B = make_float4(0.f, 0.f, 0.f, 0.f);
        float4 o2B = make_float4(0.f, 0.f, 0.f, 0.f);
        #pragma unroll 4
        for (int d = 0; d < DE; ++d) {
            float4 yzA = *(const float4*)&WA[SU_OFF + 4 * d];  // b128 broadcast
            float4 yzB = *(const float4*)&WB[SU_OFF + 4 * d];
            float w1 = wo1[d * DM];                            // b32 coalesced
            float w2 = wo2[d * DM];
            o1A = fma4(w1, yzA, o1A); o2A = fma4(w2, yzA, o2A);
            o1B = fma4(w1, yzB, o1B); o2B = fma4(w2, yzB, o2B);
        }
        float* obA = out + ((size_t)blk * SEQ_PB + 2 * wv) * NJ;
        float* obB = obA + NJ;
        *(float4*)&obA[4 * dd1] = o1A;
        *(float4*)&obB[4 * dd1] = o1B;
        if (lane < 32) {
            *(float4*)&obA[4 * dd2] = o2A;
            *(float4*)&obB[4 * dd2] = o2B;
        }
    }
}

extern "C" void kernel_launch(void* const* d_in, const int* in_sizes, int n_in,
                              void* d_out, int out_size, void* d_ws, size_t ws_size,
                              hipStream_t stream) {
    (void)n_in; (void)ws_size; (void)out_size;
    int nseq = in_sizes[0] / NJ;            // 12544 = 4*56*56
    int grid = nseq / SEQ_PB;               // 1568 blocks
    if (grid < 1) grid = 1;
    float* ws = (float*)d_ws;               // 238 KB used

    prep_weights<<<64, THREADS, 0, stream>>>(
        (const float*)d_in[1],  // in_proj_w
        (const float*)d_in[9],  // out_proj_w
        (const float*)d_in[5],  // A_logs
        (const float*)d_in[3],  // dt_projs_weight
        ws);

    ssm_fused9<<<grid, THREADS, 0, stream>>>(
        (const float*)d_in[0],  // x
        (const float*)d_in[2],  // x_proj_weight
        (const float*)d_in[4],  // dt_projs_bias
        (const float*)d_in[6],  // Ds
        (const float*)d_in[7],  // ln_gamma
        (const float*)d_in[8],  // ln_beta
        ws,
        (float*)d_out);
}